// Round 1
// baseline (1720.291 us; speedup 1.0000x reference)
//
#include <hip/hip_runtime.h>
#include <hip/hip_bf16.h>

// Exact-match requirement for FPS/KNN index selection: no FMA contraction,
// replicate numpy fp32 expression order. Conv layers use explicit fmaf.
#pragma clang fp contract(off)

#define NPTS 8192
#define NS   1024
#define NB   2
#define NC   29
#define NK   16

// ---------------- workspace layout (bytes) ----------------
// nx      float[6144]    @ 8192
// knn     int[32768]     @ 32768
// w0t     float[73728]   @ 163840
// bias0   float[64]      @ 458752
// w1t     float[36864]   @ 459008
// w2t     float[73728]   @ 606464
// w3t     float[65536]   @ 901376

// ---------------- weight prep: transpose to [K][tap][O], fold ones-channels into bias0 ----------------
__global__ __launch_bounds__(256) void prep_kernel(
    const float* __restrict__ w0, const float* __restrict__ w1,
    const float* __restrict__ w2, const float* __restrict__ w3,
    float* __restrict__ w0t, float* __restrict__ w1t,
    float* __restrict__ w2t, float* __restrict__ w3t,
    float* __restrict__ bias0)
{
    int i = blockIdx.x * 256 + threadIdx.x;
    int n = gridDim.x * 256;
    for (int e = i; e < 73728; e += n) {
        int o = e & 63, r = e >> 6, tap = r % 9, ic2 = r / 9;
        int ic = ((ic2 >> 5) << 6) + (ic2 & 31);
        w0t[e] = w0[(o * 256 + ic) * 9 + tap];
    }
    for (int e = i; e < 36864; e += n) {
        int o = e & 63, r = e >> 6, tap = r % 9, ic = r / 9;
        w1t[e] = w1[(o * 64 + ic) * 9 + tap];
    }
    for (int e = i; e < 73728; e += n) {
        int o = e & 127, r = e >> 7, tap = r % 9, ic = r / 9;
        w2t[e] = w2[(o * 64 + ic) * 9 + tap];
    }
    for (int e = i; e < 65536; e += n) {
        int o = e & 127, r = e >> 7, tap = r & 3, ic = r >> 2;
        w3t[e] = w3[(o * 128 + ic) * 4 + tap];
    }
    if (i < 64) {
        float sum = 0.0f;
        for (int q = 0; q < 4; ++q)
            for (int c = 0; c < 32; ++c)
                for (int t = 0; t < 9; ++t)
                    sum += w0[(i * 256 + q * 64 + 32 + c) * 9 + t];
        bias0[i] = sum;
    }
}

// DPP wave64 max for non-negative floats (bound_ctrl zeros are identity for max).
// row_shr 1/2/4/8 -> lane15 of each 16-row holds row max; row_bcast15 (rows 1,3)
// then row_bcast31 (rows 2,3) -> lane 63 holds full wave max.
__device__ __forceinline__ float wave_max_nonneg(float x) {
    int v = __float_as_int(x);
    int t;
    t = __builtin_amdgcn_update_dpp(0, v, 0x111, 0xf, 0xf, true);
    v = __float_as_int(fmaxf(__int_as_float(v), __int_as_float(t)));
    t = __builtin_amdgcn_update_dpp(0, v, 0x112, 0xf, 0xf, true);
    v = __float_as_int(fmaxf(__int_as_float(v), __int_as_float(t)));
    t = __builtin_amdgcn_update_dpp(0, v, 0x114, 0xf, 0xf, true);
    v = __float_as_int(fmaxf(__int_as_float(v), __int_as_float(t)));
    t = __builtin_amdgcn_update_dpp(0, v, 0x118, 0xf, 0xf, true);
    v = __float_as_int(fmaxf(__int_as_float(v), __int_as_float(t)));
    t = __builtin_amdgcn_update_dpp(0, v, 0x142, 0xa, 0xf, true);
    v = __float_as_int(fmaxf(__int_as_float(v), __int_as_float(t)));
    t = __builtin_amdgcn_update_dpp(0, v, 0x143, 0xc, 0xf, true);
    v = __float_as_int(fmaxf(__int_as_float(v), __int_as_float(t)));
    return __int_as_float(__builtin_amdgcn_readlane(v, 63));
}

// ---------------- FPS: one 256-thread block per batch, 32 pts/thread in regs ----------------
// Latency-optimized serial loop: ONE barrier per iteration.
// Per-iteration dedicated u64 key slot s_key[it] = (dist_bits<<32) | ~gi
// (dists are non-negative so float-bit order == unsigned order; ~gi makes
// u64-max resolve value-max with smallest-index tie-break == numpy argmax).
// Slots are zero-initialized once -> no reset, no second barrier, no races.
// Packed fp32 (float2 -> v_pk_add/mul_f32) halves update-issue cost; exact
// per-element order (dx*dx+dy*dy)+dz*dz preserved, fminf scalar.
typedef float v2f __attribute__((ext_vector_type(2)));

__global__ __launch_bounds__(256, 1) void fps_kernel(
    const float* __restrict__ xyz,
    float* __restrict__ nx_ws, float* __restrict__ out)
{
    int b = blockIdx.x;
    int tid = threadIdx.x;              // 0..255
    int lane = tid & 63;
    const float* X = xyz + b * 3 * NPTS;

    __shared__ unsigned long long s_key[NS];   // 8 KB

    // point pair i holds gi = i*512 + tid*2 + {0,1}
    v2f px[16], py[16], pz[16], dist[16];

    for (int i = tid; i < NS; i += 256) s_key[i] = 0ull;
    if (tid == 0) s_key[0] = 0xFFFFFFFFull;    // idx 0 forced (value field unused)

#pragma unroll
    for (int i = 0; i < 16; ++i) {
        int g2 = i * 512 + tid * 2;
        px[i] = *(const v2f*)(X + g2);
        py[i] = *(const v2f*)(X + NPTS + g2);
        pz[i] = *(const v2f*)(X + 2 * NPTS + g2);
        dist[i] = (v2f){1e10f, 1e10f};
    }
    __syncthreads();

    float cx = X[0], cy = X[NPTS], cz = X[2 * NPTS];

    for (int it = 1; it < NS; ++it) {
        v2f c2x = {cx, cx}, c2y = {cy, cy}, c2z = {cz, cz};
        // ---- update dists (exact numpy order, no fma; packed fp32) ----
#pragma unroll
        for (int i = 0; i < 16; ++i) {
            v2f dx = px[i] - c2x, dy = py[i] - c2y, dz = pz[i] - c2z;
            v2f d = (dx * dx + dy * dy) + dz * dz;
            v2f dd = dist[i];
            dd.x = fminf(dd.x, d.x);
            dd.y = fminf(dd.y, d.y);
            dist[i] = dd;
        }
        // ---- local value max, explicit tree (depth 6, all indices static) ----
        float t16[16];
#pragma unroll
        for (int i = 0; i < 16; ++i) t16[i] = fmaxf(dist[i].x, dist[i].y);
        float t8[8];
#pragma unroll
        for (int i = 0; i < 8; ++i) t8[i] = fmaxf(t16[2 * i], t16[2 * i + 1]);
        float t4[4];
#pragma unroll
        for (int i = 0; i < 4; ++i) t4[i] = fmaxf(t8[2 * i], t8[2 * i + 1]);
        float bv = fmaxf(fmaxf(t4[0], t4[1]), fmaxf(t4[2], t4[3]));
        // ---- wave max via DPP; winner lanes resolve first-index + one atomic ----
        float wm = wave_max_nonneg(bv);
        if (bv == wm) {
            int gi = 0;
#pragma unroll
            for (int i = 15; i >= 0; --i) {          // descending -> ends at smallest gi
                if (dist[i].y == wm) gi = i * 512 + tid * 2 + 1;
                if (dist[i].x == wm) gi = i * 512 + tid * 2;
            }
            unsigned long long key =
                ((unsigned long long)__float_as_uint(wm) << 32) | (unsigned)(~gi);
            atomicMax(&s_key[it], key);
        }
        __syncthreads();
        int idx = (int)(~(unsigned)s_key[it]);
        // centroid re-fetch: same-address broadcast load, L2-resident (96 KB input)
        cx = X[idx]; cy = X[NPTS + idx]; cz = X[2 * NPTS + idx];
    }

    // ---- outputs: fps indices + gathered new_xyz (all slots final after last barrier) ----
    float* out_fps = out + 268288 + b * NS;
    for (int i = tid; i < NS; i += 256) {
        int j = (int)(~(unsigned)s_key[i]);
        out_fps[i] = (float)j;
        float x = X[j], y = X[NPTS + j], z = X[2 * NPTS + j];
        nx_ws[(b * 3 + 0) * NS + i] = x; out[(b * 3 + 0) * NS + i] = x;
        nx_ws[(b * 3 + 1) * NS + i] = y; out[(b * 3 + 1) * NS + i] = y;
        nx_ws[(b * 3 + 2) * NS + i] = z; out[(b * 3 + 2) * NS + i] = z;
    }
}

// ---------------- KNN: one wave per query ----------------
__global__ __launch_bounds__(256) void knn_kernel(
    const float* __restrict__ nx_ws, int* __restrict__ knn_ws)
{
    int q = blockIdx.x * 4 + (threadIdx.x >> 6);
    int lane = threadIdx.x & 63;
    int b = q >> 10, s = q & 1023;
    const float* P = nx_ws + b * 3 * NS;
    float qx = P[s], qy = P[NS + s], qz = P[2 * NS + s];
    float sqq = (qx * qx + qy * qy) + qz * qz;
    int base_j = lane * 16;
    float d2[16];
    {
        const float4* x4 = (const float4*)(P + base_j);
        const float4* y4 = (const float4*)(P + NS + base_j);
        const float4* z4 = (const float4*)(P + 2 * NS + base_j);
#pragma unroll
        for (int t = 0; t < 4; ++t) {
            float4 xv = x4[t], yv = y4[t], zv = z4[t];
            float xs[4] = { xv.x, xv.y, xv.z, xv.w };
            float ys[4] = { yv.x, yv.y, yv.z, yv.w };
            float zs[4] = { zv.x, zv.y, zv.z, zv.w };
#pragma unroll
            for (int e = 0; e < 4; ++e) {
                float xj = xs[e], yj = ys[e], zj = zs[e];
                float sqj = (xj * xj + yj * yj) + zj * zj;
                float dot = (qx * xj + qy * yj) + qz * zj;
                d2[t * 4 + e] = (sqq + sqj) - 2.0f * dot;   // numpy order
            }
        }
    }
    for (int r = 0; r < NK; ++r) {
        float lv = 3.0e38f; int li = 0;
#pragma unroll
        for (int i = 0; i < 16; ++i) { if (d2[i] < lv) { lv = d2[i]; li = i; } } // strict < keeps earliest
        int gj = base_j + li;
#pragma unroll
        for (int off = 32; off > 0; off >>= 1) {
            float ov = __shfl_xor(lv, off, 64);
            int   oj = __shfl_xor(gj, off, 64);
            if (ov < lv || (ov == lv && oj < gj)) { lv = ov; gj = oj; }
        }
        if (lane == 0) knn_ws[q * NK + r] = gj;
        if ((gj >> 4) == lane) {
            int li2 = gj & 15;
#pragma unroll
            for (int i = 0; i < 16; ++i) if (i == li2) d2[i] = 3.0e38f;
        }
    }
}

// ---------------- conv0 inner helper (positions compile-time per parity of g) ----------------
template<int GODD>
__device__ __forceinline__ void conv0_accum(
    const float* __restrict__ x0r, const float* __restrict__ wbase, float acc[9])
{
    for (int ic2 = 0; ic2 < 128; ++ic2) {
        const float4* x4 = (const float4*)(x0r + ic2 * 64);
        float rr[32];
#pragma unroll
        for (int j = 0; j < 4; ++j) {
            float4 t0 = x4[j * 2], t1 = x4[j * 2 + 1];
            rr[j*8+0]=t0.x; rr[j*8+1]=t0.y; rr[j*8+2]=t0.z; rr[j*8+3]=t0.w;
            rr[j*8+4]=t1.x; rr[j*8+5]=t1.y; rr[j*8+6]=t1.z; rr[j*8+7]=t1.w;
        }
        float w[9];
#pragma unroll
        for (int t = 0; t < 9; ++t) w[t] = wbase[(ic2 * 9 + t) * 64];
#pragma unroll
        for (int pp = 0; pp < 9; ++pp) {
            const int ly = GODD ? (pp < 3 ? 0 : 1) : (pp < 6 ? 0 : 1);
            const int xx = GODD ? (pp < 3 ? pp + 3 : pp - 3) : (pp < 6 ? pp : pp - 6);
#pragma unroll
            for (int ky = 0; ky < 3; ++ky)
#pragma unroll
                for (int kx = 0; kx < 3; ++kx)
                    acc[pp] = __builtin_fmaf(w[ky * 3 + kx], rr[(ly + ky) * 8 + xx + kx], acc[pp]);
        }
    }
}

// ---------------- per-sample conv chain ----------------
__global__ __launch_bounds__(256) void conv_kernel(
    const float* __restrict__ feats, const float* __restrict__ nx_ws,
    const int* __restrict__ knn_ws,
    const float* __restrict__ w0t, const float* __restrict__ bias0,
    const float* __restrict__ w1t, const float* __restrict__ w2t,
    const float* __restrict__ w3t, float* __restrict__ out)
{
    __shared__ float s_fg[512];       // [d][k]
    __shared__ int   s_ni[16];
    __shared__ float s_x0[8192];      // [ic2][u*8+v], outer channels only
    __shared__ float s_a1[64 * 36];
    __shared__ float s_a2[64 * 16];
    __shared__ float s_a3[128 * 4];

    int bs = blockIdx.x, b = bs >> 10, s = bs & 1023;
    int tid = threadIdx.x;
    if (tid < 16) s_ni[tid] = knn_ws[bs * NK + tid];
    __syncthreads();
    const float* P = nx_ws + b * 3 * NS;
#pragma unroll
    for (int e = tid; e < 512; e += 256) {
        int d = e >> 4, k = e & 15; int j = s_ni[k];
        float v = (d < 3) ? (P[d * NS + j] - P[d * NS + s])
                          : feats[(b * NC + (d - 3)) * NPTS + j];
        s_fg[e] = v;
    }
    __syncthreads();
    for (int e = tid; e < 8192; e += 256) {
        int ic2 = e >> 6, pos = e & 63, u = pos >> 3, v = pos & 7;
        int q = ic2 >> 5, ch = ic2 & 31;
        int ro = q & 1, co = ((q + 1) >> 1) & 1;    // tl,br,tr,bl
        s_x0[e] = s_fg[ch * 16 + 2 * u + ro] * s_fg[ch * 16 + 2 * v + co];
    }
    __syncthreads();

    int o = tid & 63, g = tid >> 6;
    { // conv0: 64 out-ch x 6x6, K = 128x9 (+ bias from ones-channels)
        int r0 = g + (g >> 1);
        float acc[9];
        float bz = bias0[o];
#pragma unroll
        for (int p = 0; p < 9; ++p) acc[p] = bz;
        const float* x0r = s_x0 + r0 * 8;
        const float* wb = w0t + o;
        if (g & 1) conv0_accum<1>(x0r, wb, acc);
        else       conv0_accum<0>(x0r, wb, acc);
#pragma unroll
        for (int pp = 0; pp < 9; ++pp) s_a1[o * 36 + g * 9 + pp] = fmaxf(acc[pp], 0.0f);
    }
    __syncthreads();
    { // conv1: 64 x 4x4, K = 64x9 ; y = g
        float a[4] = {0, 0, 0, 0};
        const float* wb = w1t + o;
        for (int ic = 0; ic < 64; ++ic) {
            const float2* ar2 = (const float2*)(s_a1 + ic * 36 + g * 6);
            float r[18];
#pragma unroll
            for (int t = 0; t < 9; ++t) { float2 tv = ar2[t]; r[t*2] = tv.x; r[t*2+1] = tv.y; }
            float w[9];
#pragma unroll
            for (int t = 0; t < 9; ++t) w[t] = wb[(ic * 9 + t) * 64];
#pragma unroll
            for (int x = 0; x < 4; ++x)
#pragma unroll
                for (int ky = 0; ky < 3; ++ky)
#pragma unroll
                    for (int kx = 0; kx < 3; ++kx)
                        a[x] = __builtin_fmaf(w[ky * 3 + kx], r[ky * 6 + x + kx], a[x]);
        }
#pragma unroll
        for (int x = 0; x < 4; ++x) s_a2[o * 16 + g * 4 + x] = fmaxf(a[x], 0.0f);
    }
    __syncthreads();
    { // conv2: 128 x 2x2, K = 64x9 ; y = g2
        int o2 = tid & 127, g2 = tid >> 7;
        float a[2] = {0, 0};
        const float* wb = w2t + o2;
        for (int ic = 0; ic < 64; ++ic) {
            const float4* ar4 = (const float4*)(s_a2 + ic * 16 + g2 * 4);
            float r[12];
#pragma unroll
            for (int t = 0; t < 3; ++t) { float4 tv = ar4[t]; r[t*4]=tv.x; r[t*4+1]=tv.y; r[t*4+2]=tv.z; r[t*4+3]=tv.w; }
            float w[9];
#pragma unroll
            for (int t = 0; t < 9; ++t) w[t] = wb[(ic * 9 + t) * 128];
#pragma unroll
            for (int x = 0; x < 2; ++x)
#pragma unroll
                for (int ky = 0; ky < 3; ++ky)
#pragma unroll
                    for (int kx = 0; kx < 3; ++kx)
                        a[x] = __builtin_fmaf(w[ky * 3 + kx], r[ky * 4 + x + kx], a[x]);
        }
#pragma unroll
        for (int x = 0; x < 2; ++x) s_a3[o2 * 4 + g2 * 2 + x] = fmaxf(a[x], 0.0f);
    }
    __syncthreads();
    // conv3: 128 out, K = 128x4 -> 1x1, relu, write new_points
    if (tid < 128) {
        float acc = 0.0f;
        const float* wb = w3t + tid;
        for (int ic = 0; ic < 128; ++ic) {
            float4 av = *(const float4*)(s_a3 + ic * 4);
            float wa = wb[(ic * 4 + 0) * 128];
            float wbv = wb[(ic * 4 + 1) * 128];
            float wc = wb[(ic * 4 + 2) * 128];
            float wd = wb[(ic * 4 + 3) * 128];
            acc = __builtin_fmaf(wa, av.x, acc);
            acc = __builtin_fmaf(wbv, av.y, acc);
            acc = __builtin_fmaf(wc, av.z, acc);
            acc = __builtin_fmaf(wd, av.w, acc);
        }
        out[6144 + (b * 128 + tid) * NS + s] = fmaxf(acc, 0.0f);
    }
}

extern "C" void kernel_launch(void* const* d_in, const int* in_sizes, int n_in,
                              void* d_out, int out_size, void* d_ws, size_t ws_size,
                              hipStream_t stream) {
    const float* xyz   = (const float*)d_in[0];
    const float* feats = (const float*)d_in[1];
    const float* w0    = (const float*)d_in[2];
    const float* w1    = (const float*)d_in[3];
    const float* w2    = (const float*)d_in[4];
    const float* w3    = (const float*)d_in[5];
    float* out = (float*)d_out;

    char* ws = (char*)d_ws;
    float* nx_ws  = (float*)(ws + 8192);
    int*   knn_ws = (int*)(ws + 32768);
    float* w0t    = (float*)(ws + 163840);
    float* bias0  = (float*)(ws + 458752);
    float* w1t    = (float*)(ws + 459008);
    float* w2t    = (float*)(ws + 606464);
    float* w3t    = (float*)(ws + 901376);

    prep_kernel<<<128, 256, 0, stream>>>(w0, w1, w2, w3, w0t, w1t, w2t, w3t, bias0);
    fps_kernel<<<NB, 256, 0, stream>>>(xyz, nx_ws, out);
    knn_kernel<<<(NB * NS) / 4, 256, 0, stream>>>(nx_ws, knn_ws);
    conv_kernel<<<NB * NS, 256, 0, stream>>>(feats, nx_ws, knn_ws, w0t, bias0, w1t, w2t, w3t, out);
}

// Round 2
// 1462.821 us; speedup vs baseline: 1.1760x; 1.1760x over previous
//
#include <hip/hip_runtime.h>
#include <hip/hip_bf16.h>

// Exact-match requirement for FPS/KNN index selection: no FMA contraction,
// replicate numpy fp32 expression order. Conv layers use explicit fmaf.
#pragma clang fp contract(off)

#define NPTS 8192
#define NS   1024
#define NB   2
#define NC   29
#define NK   16

// ---------------- workspace layout (bytes) ----------------
// nx      float[6144]    @ 8192
// knn     int[32768]     @ 32768
// w0t     float[73728]   @ 163840
// bias0   float[64]      @ 458752
// w1t     float[36864]   @ 459008
// w2t     float[73728]   @ 606464
// w3t     float[65536]   @ 901376

// ---------------- weight prep: transpose to [K][tap][O], fold ones-channels into bias0 ----------------
__global__ __launch_bounds__(256) void prep_kernel(
    const float* __restrict__ w0, const float* __restrict__ w1,
    const float* __restrict__ w2, const float* __restrict__ w3,
    float* __restrict__ w0t, float* __restrict__ w1t,
    float* __restrict__ w2t, float* __restrict__ w3t,
    float* __restrict__ bias0)
{
    int i = blockIdx.x * 256 + threadIdx.x;
    int n = gridDim.x * 256;
    for (int e = i; e < 73728; e += n) {
        int o = e & 63, r = e >> 6, tap = r % 9, ic2 = r / 9;
        int ic = ((ic2 >> 5) << 6) + (ic2 & 31);
        w0t[e] = w0[(o * 256 + ic) * 9 + tap];
    }
    for (int e = i; e < 36864; e += n) {
        int o = e & 63, r = e >> 6, tap = r % 9, ic = r / 9;
        w1t[e] = w1[(o * 64 + ic) * 9 + tap];
    }
    for (int e = i; e < 73728; e += n) {
        int o = e & 127, r = e >> 7, tap = r % 9, ic = r / 9;
        w2t[e] = w2[(o * 64 + ic) * 9 + tap];
    }
    for (int e = i; e < 65536; e += n) {
        int o = e & 127, r = e >> 7, tap = r & 3, ic = r >> 2;
        w3t[e] = w3[(o * 128 + ic) * 4 + tap];
    }
    if (i < 64) {
        float sum = 0.0f;
        for (int q = 0; q < 4; ++q)
            for (int c = 0; c < 32; ++c)
                for (int t = 0; t < 9; ++t)
                    sum += w0[(i * 256 + q * 64 + 32 + c) * 9 + t];
        bias0[i] = sum;
    }
}

// DPP wave64 max for non-negative floats (bound_ctrl zeros are identity for max).
// row_shr 1/2/4/8 -> lane15 of each 16-row holds row max; row_bcast15 (rows 1,3)
// then row_bcast31 (rows 2,3) -> lane 63 holds full wave max.
__device__ __forceinline__ float wave_max_nonneg(float x) {
    int v = __float_as_int(x);
    int t;
    t = __builtin_amdgcn_update_dpp(0, v, 0x111, 0xf, 0xf, true);
    v = __float_as_int(fmaxf(__int_as_float(v), __int_as_float(t)));
    t = __builtin_amdgcn_update_dpp(0, v, 0x112, 0xf, 0xf, true);
    v = __float_as_int(fmaxf(__int_as_float(v), __int_as_float(t)));
    t = __builtin_amdgcn_update_dpp(0, v, 0x114, 0xf, 0xf, true);
    v = __float_as_int(fmaxf(__int_as_float(v), __int_as_float(t)));
    t = __builtin_amdgcn_update_dpp(0, v, 0x118, 0xf, 0xf, true);
    v = __float_as_int(fmaxf(__int_as_float(v), __int_as_float(t)));
    t = __builtin_amdgcn_update_dpp(0, v, 0x142, 0xa, 0xf, true);
    v = __float_as_int(fmaxf(__int_as_float(v), __int_as_float(t)));
    t = __builtin_amdgcn_update_dpp(0, v, 0x143, 0xc, 0xf, true);
    v = __float_as_int(fmaxf(__int_as_float(v), __int_as_float(t)));
    return __int_as_float(__builtin_amdgcn_readlane(v, 63));
}

// ---------------- FPS: one 1024-thread block per batch, 8 pts/thread in regs ----------------
// Structure notes (hard-won):
//  * 1024 threads (16 waves) >> 256 threads (4 waves): this loop is
//    latency-bound; TLP is the only thing hiding LDS/L2/atomic latency.
//    (256-thr variant measured 1388 us vs 1053 us despite fewer issue slots.)
//  * One barrier per iteration: per-iteration dedicated u64 key slot
//    s_key[it] = (dist_bits<<32) | ~gi. dists >= 0 so float-bit order ==
//    unsigned order; ~gi makes u64-max == value-max with smallest-index
//    tie-break == numpy argmax. Slots zero-initialized once; no reset, no
//    second barrier, no races (slot `it` only written before barrier `it`).
//  * px/py/pz pinned in VGPRs via empty asm: the allocator otherwise
//    rematerializes them from global every iteration (round-0 VGPR_Count=28
//    proves it), putting 24 L1/L2 loads on the serial chain.
//  * Winner-lane resolve: only lanes with bv==wm scan their 8 dists
//    (descending -> smallest index) and issue one LDS atomicMax each.
__global__ __launch_bounds__(1024) void fps_kernel(
    const float* __restrict__ xyz,
    float* __restrict__ nx_ws, float* __restrict__ out)
{
    int b = blockIdx.x;
    int tid = threadIdx.x;
    const float* X = xyz + b * 3 * NPTS;

    __shared__ unsigned long long s_key[NS];   // 8 KB

    float px[8], py[8], pz[8], dist[8];
#pragma unroll
    for (int i = 0; i < 8; ++i) {
        int gi = i * 1024 + tid;                // point index == (i<<10)+tid
        px[i] = X[gi];
        py[i] = X[NPTS + gi];
        pz[i] = X[2 * NPTS + gi];
        dist[i] = 1e10f;
    }
    // Pin coords in VGPRs: opaque to the compiler -> no remat-from-global.
#pragma unroll
    for (int i = 0; i < 8; ++i) {
        asm volatile("" : "+v"(px[i]), "+v"(py[i]), "+v"(pz[i]));
    }

    s_key[tid] = 0ull;
    if (tid == 0) s_key[0] = 0xFFFFFFFFull;    // idx 0 forced (value field unused)
    __syncthreads();

    float cx = X[0], cy = X[NPTS], cz = X[2 * NPTS];

    for (int it = 1; it < NS; ++it) {
        // ---- update dists (exact numpy order, no fma) ----
#pragma unroll
        for (int i = 0; i < 8; ++i) {
            float dx = px[i] - cx, dy = py[i] - cy, dz = pz[i] - cz;
            float d = (dx * dx + dy * dy) + dz * dz;
            dist[i] = fminf(dist[i], d);
        }
        // ---- local value max (tree, 7 ops) ----
        float m0 = fmaxf(dist[0], dist[1]);
        float m1 = fmaxf(dist[2], dist[3]);
        float m2 = fmaxf(dist[4], dist[5]);
        float m3 = fmaxf(dist[6], dist[7]);
        float bv = fmaxf(fmaxf(m0, m1), fmaxf(m2, m3));
        // ---- wave max via DPP; winner lanes resolve first-index + one atomic ----
        float wm = wave_max_nonneg(bv);
        if (bv == wm) {
            int gi = 0;
#pragma unroll
            for (int i = 7; i >= 0; --i)
                if (dist[i] == wm) gi = (i << 10) + tid;   // ends at smallest i
            unsigned long long key =
                ((unsigned long long)__float_as_uint(wm) << 32) | (unsigned)(~gi);
            atomicMax(&s_key[it], key);
        }
        __syncthreads();
        // wave-uniform index -> scalar centroid fetch through sL1
        int idx = __builtin_amdgcn_readfirstlane((int)(~(unsigned)s_key[it]));
        cx = X[idx]; cy = X[NPTS + idx]; cz = X[2 * NPTS + idx];
    }

    // ---- outputs: fps indices + gathered new_xyz (all slots final) ----
    float* out_fps = out + 268288 + b * NS;
    {
        int j = (int)(~(unsigned)s_key[tid]);
        out_fps[tid] = (float)j;
        float x = X[j], y = X[NPTS + j], z = X[2 * NPTS + j];
        nx_ws[(b * 3 + 0) * NS + tid] = x; out[(b * 3 + 0) * NS + tid] = x;
        nx_ws[(b * 3 + 1) * NS + tid] = y; out[(b * 3 + 1) * NS + tid] = y;
        nx_ws[(b * 3 + 2) * NS + tid] = z; out[(b * 3 + 2) * NS + tid] = z;
    }
}

// ---------------- KNN: one wave per query ----------------
__global__ __launch_bounds__(256) void knn_kernel(
    const float* __restrict__ nx_ws, int* __restrict__ knn_ws)
{
    int q = blockIdx.x * 4 + (threadIdx.x >> 6);
    int lane = threadIdx.x & 63;
    int b = q >> 10, s = q & 1023;
    const float* P = nx_ws + b * 3 * NS;
    float qx = P[s], qy = P[NS + s], qz = P[2 * NS + s];
    float sqq = (qx * qx + qy * qy) + qz * qz;
    int base_j = lane * 16;
    float d2[16];
    {
        const float4* x4 = (const float4*)(P + base_j);
        const float4* y4 = (const float4*)(P + NS + base_j);
        const float4* z4 = (const float4*)(P + 2 * NS + base_j);
#pragma unroll
        for (int t = 0; t < 4; ++t) {
            float4 xv = x4[t], yv = y4[t], zv = z4[t];
            float xs[4] = { xv.x, xv.y, xv.z, xv.w };
            float ys[4] = { yv.x, yv.y, yv.z, yv.w };
            float zs[4] = { zv.x, zv.y, zv.z, zv.w };
#pragma unroll
            for (int e = 0; e < 4; ++e) {
                float xj = xs[e], yj = ys[e], zj = zs[e];
                float sqj = (xj * xj + yj * yj) + zj * zj;
                float dot = (qx * xj + qy * yj) + qz * zj;
                d2[t * 4 + e] = (sqq + sqj) - 2.0f * dot;   // numpy order
            }
        }
    }
    for (int r = 0; r < NK; ++r) {
        float lv = 3.0e38f; int li = 0;
#pragma unroll
        for (int i = 0; i < 16; ++i) { if (d2[i] < lv) { lv = d2[i]; li = i; } } // strict < keeps earliest
        int gj = base_j + li;
#pragma unroll
        for (int off = 32; off > 0; off >>= 1) {
            float ov = __shfl_xor(lv, off, 64);
            int   oj = __shfl_xor(gj, off, 64);
            if (ov < lv || (ov == lv && oj < gj)) { lv = ov; gj = oj; }
        }
        if (lane == 0) knn_ws[q * NK + r] = gj;
        if ((gj >> 4) == lane) {
            int li2 = gj & 15;
#pragma unroll
            for (int i = 0; i < 16; ++i) if (i == li2) d2[i] = 3.0e38f;
        }
    }
}

// ---------------- conv0 inner helper (positions compile-time per parity of g) ----------------
template<int GODD>
__device__ __forceinline__ void conv0_accum(
    const float* __restrict__ x0r, const float* __restrict__ wbase, float acc[9])
{
    for (int ic2 = 0; ic2 < 128; ++ic2) {
        const float4* x4 = (const float4*)(x0r + ic2 * 64);
        float rr[32];
#pragma unroll
        for (int j = 0; j < 4; ++j) {
            float4 t0 = x4[j * 2], t1 = x4[j * 2 + 1];
            rr[j*8+0]=t0.x; rr[j*8+1]=t0.y; rr[j*8+2]=t0.z; rr[j*8+3]=t0.w;
            rr[j*8+4]=t1.x; rr[j*8+5]=t1.y; rr[j*8+6]=t1.z; rr[j*8+7]=t1.w;
        }
        float w[9];
#pragma unroll
        for (int t = 0; t < 9; ++t) w[t] = wbase[(ic2 * 9 + t) * 64];
#pragma unroll
        for (int pp = 0; pp < 9; ++pp) {
            const int ly = GODD ? (pp < 3 ? 0 : 1) : (pp < 6 ? 0 : 1);
            const int xx = GODD ? (pp < 3 ? pp + 3 : pp - 3) : (pp < 6 ? pp : pp - 6);
#pragma unroll
            for (int ky = 0; ky < 3; ++ky)
#pragma unroll
                for (int kx = 0; kx < 3; ++kx)
                    acc[pp] = __builtin_fmaf(w[ky * 3 + kx], rr[(ly + ky) * 8 + xx + kx], acc[pp]);
        }
    }
}

// ---------------- per-sample conv chain ----------------
__global__ __launch_bounds__(256) void conv_kernel(
    const float* __restrict__ feats, const float* __restrict__ nx_ws,
    const int* __restrict__ knn_ws,
    const float* __restrict__ w0t, const float* __restrict__ bias0,
    const float* __restrict__ w1t, const float* __restrict__ w2t,
    const float* __restrict__ w3t, float* __restrict__ out)
{
    __shared__ float s_fg[512];       // [d][k]
    __shared__ int   s_ni[16];
    __shared__ float s_x0[8192];      // [ic2][u*8+v], outer channels only
    __shared__ float s_a1[64 * 36];
    __shared__ float s_a2[64 * 16];
    __shared__ float s_a3[128 * 4];

    int bs = blockIdx.x, b = bs >> 10, s = bs & 1023;
    int tid = threadIdx.x;
    if (tid < 16) s_ni[tid] = knn_ws[bs * NK + tid];
    __syncthreads();
    const float* P = nx_ws + b * 3 * NS;
#pragma unroll
    for (int e = tid; e < 512; e += 256) {
        int d = e >> 4, k = e & 15; int j = s_ni[k];
        float v = (d < 3) ? (P[d * NS + j] - P[d * NS + s])
                          : feats[(b * NC + (d - 3)) * NPTS + j];
        s_fg[e] = v;
    }
    __syncthreads();
    for (int e = tid; e < 8192; e += 256) {
        int ic2 = e >> 6, pos = e & 63, u = pos >> 3, v = pos & 7;
        int q = ic2 >> 5, ch = ic2 & 31;
        int ro = q & 1, co = ((q + 1) >> 1) & 1;    // tl,br,tr,bl
        s_x0[e] = s_fg[ch * 16 + 2 * u + ro] * s_fg[ch * 16 + 2 * v + co];
    }
    __syncthreads();

    int o = tid & 63, g = tid >> 6;
    { // conv0: 64 out-ch x 6x6, K = 128x9 (+ bias from ones-channels)
        int r0 = g + (g >> 1);
        float acc[9];
        float bz = bias0[o];
#pragma unroll
        for (int p = 0; p < 9; ++p) acc[p] = bz;
        const float* x0r = s_x0 + r0 * 8;
        const float* wb = w0t + o;
        if (g & 1) conv0_accum<1>(x0r, wb, acc);
        else       conv0_accum<0>(x0r, wb, acc);
#pragma unroll
        for (int pp = 0; pp < 9; ++pp) s_a1[o * 36 + g * 9 + pp] = fmaxf(acc[pp], 0.0f);
    }
    __syncthreads();
    { // conv1: 64 x 4x4, K = 64x9 ; y = g
        float a[4] = {0, 0, 0, 0};
        const float* wb = w1t + o;
        for (int ic = 0; ic < 64; ++ic) {
            const float2* ar2 = (const float2*)(s_a1 + ic * 36 + g * 6);
            float r[18];
#pragma unroll
            for (int t = 0; t < 9; ++t) { float2 tv = ar2[t]; r[t*2] = tv.x; r[t*2+1] = tv.y; }
            float w[9];
#pragma unroll
            for (int t = 0; t < 9; ++t) w[t] = wb[(ic * 9 + t) * 64];
#pragma unroll
            for (int x = 0; x < 4; ++x)
#pragma unroll
                for (int ky = 0; ky < 3; ++ky)
#pragma unroll
                    for (int kx = 0; kx < 3; ++kx)
                        a[x] = __builtin_fmaf(w[ky * 3 + kx], r[ky * 6 + x + kx], a[x]);
        }
#pragma unroll
        for (int x = 0; x < 4; ++x) s_a2[o * 16 + g * 4 + x] = fmaxf(a[x], 0.0f);
    }
    __syncthreads();
    { // conv2: 128 x 2x2, K = 64x9 ; y = g2
        int o2 = tid & 127, g2 = tid >> 7;
        float a[2] = {0, 0};
        const float* wb = w2t + o2;
        for (int ic = 0; ic < 64; ++ic) {
            const float4* ar4 = (const float4*)(s_a2 + ic * 16 + g2 * 4);
            float r[12];
#pragma unroll
            for (int t = 0; t < 3; ++t) { float4 tv = ar4[t]; r[t*4]=tv.x; r[t*4+1]=tv.y; r[t*4+2]=tv.z; r[t*4+3]=tv.w; }
            float w[9];
#pragma unroll
            for (int t = 0; t < 9; ++t) w[t] = wb[(ic * 9 + t) * 128];
#pragma unroll
            for (int x = 0; x < 2; ++x)
#pragma unroll
                for (int ky = 0; ky < 3; ++ky)
#pragma unroll
                    for (int kx = 0; kx < 3; ++kx)
                        a[x] = __builtin_fmaf(w[ky * 3 + kx], r[ky * 4 + x + kx], a[x]);
        }
#pragma unroll
        for (int x = 0; x < 2; ++x) s_a3[o2 * 4 + g2 * 2 + x] = fmaxf(a[x], 0.0f);
    }
    __syncthreads();
    // conv3: 128 out, K = 128x4 -> 1x1, relu, write new_points
    if (tid < 128) {
        float acc = 0.0f;
        const float* wb = w3t + tid;
        for (int ic = 0; ic < 128; ++ic) {
            float4 av = *(const float4*)(s_a3 + ic * 4);
            float wa = wb[(ic * 4 + 0) * 128];
            float wbv = wb[(ic * 4 + 1) * 128];
            float wc = wb[(ic * 4 + 2) * 128];
            float wd = wb[(ic * 4 + 3) * 128];
            acc = __builtin_fmaf(wa, av.x, acc);
            acc = __builtin_fmaf(wbv, av.y, acc);
            acc = __builtin_fmaf(wc, av.z, acc);
            acc = __builtin_fmaf(wd, av.w, acc);
        }
        out[6144 + (b * 128 + tid) * NS + s] = fmaxf(acc, 0.0f);
    }
}

extern "C" void kernel_launch(void* const* d_in, const int* in_sizes, int n_in,
                              void* d_out, int out_size, void* d_ws, size_t ws_size,
                              hipStream_t stream) {
    const float* xyz   = (const float*)d_in[0];
    const float* feats = (const float*)d_in[1];
    const float* w0    = (const float*)d_in[2];
    const float* w1    = (const float*)d_in[3];
    const float* w2    = (const float*)d_in[4];
    const float* w3    = (const float*)d_in[5];
    float* out = (float*)d_out;

    char* ws = (char*)d_ws;
    float* nx_ws  = (float*)(ws + 8192);
    int*   knn_ws = (int*)(ws + 32768);
    float* w0t    = (float*)(ws + 163840);
    float* bias0  = (float*)(ws + 458752);
    float* w1t    = (float*)(ws + 459008);
    float* w2t    = (float*)(ws + 606464);
    float* w3t    = (float*)(ws + 901376);

    prep_kernel<<<128, 256, 0, stream>>>(w0, w1, w2, w3, w0t, w1t, w2t, w3t, bias0);
    fps_kernel<<<NB, 1024, 0, stream>>>(xyz, nx_ws, out);
    knn_kernel<<<(NB * NS) / 4, 256, 0, stream>>>(nx_ws, knn_ws);
    conv_kernel<<<NB * NS, 256, 0, stream>>>(feats, nx_ws, knn_ws, w0t, bias0, w1t, w2t, w3t, out);
}

// Round 3
// 1401.808 us; speedup vs baseline: 1.2272x; 1.0435x over previous
//
#include <hip/hip_runtime.h>
#include <hip/hip_bf16.h>

// Exact-match requirement for FPS/KNN index selection: no FMA contraction,
// replicate numpy fp32 expression order. Conv layers use explicit fmaf.
#pragma clang fp contract(off)

#define NPTS 8192
#define NS   1024
#define NB   2
#define NC   29
#define NK   16

// ---------------- workspace layout (bytes) ----------------
// nx      float[6144]    @ 8192
// knn     int[32768]     @ 32768
// w0t     float[73728]   @ 163840
// bias0   float[64]      @ 458752
// w1t     float[36864]   @ 459008
// w2t     float[73728]   @ 606464
// w3t     float[65536]   @ 901376

// ---------------- weight prep: transpose to [K][tap][O], fold ones-channels into bias0 ----------------
__global__ __launch_bounds__(256) void prep_kernel(
    const float* __restrict__ w0, const float* __restrict__ w1,
    const float* __restrict__ w2, const float* __restrict__ w3,
    float* __restrict__ w0t, float* __restrict__ w1t,
    float* __restrict__ w2t, float* __restrict__ w3t,
    float* __restrict__ bias0)
{
    int i = blockIdx.x * 256 + threadIdx.x;
    int n = gridDim.x * 256;
    for (int e = i; e < 73728; e += n) {
        int o = e & 63, r = e >> 6, tap = r % 9, ic2 = r / 9;
        int ic = ((ic2 >> 5) << 6) + (ic2 & 31);
        w0t[e] = w0[(o * 256 + ic) * 9 + tap];
    }
    for (int e = i; e < 36864; e += n) {
        int o = e & 63, r = e >> 6, tap = r % 9, ic = r / 9;
        w1t[e] = w1[(o * 64 + ic) * 9 + tap];
    }
    for (int e = i; e < 73728; e += n) {
        int o = e & 127, r = e >> 7, tap = r % 9, ic = r / 9;
        w2t[e] = w2[(o * 64 + ic) * 9 + tap];
    }
    for (int e = i; e < 65536; e += n) {
        int o = e & 127, r = e >> 7, tap = r & 3, ic = r >> 2;
        w3t[e] = w3[(o * 128 + ic) * 4 + tap];
    }
    if (i < 64) {
        float sum = 0.0f;
        for (int q = 0; q < 4; ++q)
            for (int c = 0; c < 32; ++c)
                for (int t = 0; t < 9; ++t)
                    sum += w0[(i * 256 + q * 64 + 32 + c) * 9 + t];
        bias0[i] = sum;
    }
}

// DPP wave64 max for non-negative floats (bound_ctrl zeros are identity for max).
// row_shr 1/2/4/8 -> lane15 of each 16-row holds row max; row_bcast15 (rows 1,3)
// then row_bcast31 (rows 2,3) -> lane 63 holds full wave max.
__device__ __forceinline__ float wave_max_nonneg(float x) {
    int v = __float_as_int(x);
    int t;
    t = __builtin_amdgcn_update_dpp(0, v, 0x111, 0xf, 0xf, true);
    v = __float_as_int(fmaxf(__int_as_float(v), __int_as_float(t)));
    t = __builtin_amdgcn_update_dpp(0, v, 0x112, 0xf, 0xf, true);
    v = __float_as_int(fmaxf(__int_as_float(v), __int_as_float(t)));
    t = __builtin_amdgcn_update_dpp(0, v, 0x114, 0xf, 0xf, true);
    v = __float_as_int(fmaxf(__int_as_float(v), __int_as_float(t)));
    t = __builtin_amdgcn_update_dpp(0, v, 0x118, 0xf, 0xf, true);
    v = __float_as_int(fmaxf(__int_as_float(v), __int_as_float(t)));
    t = __builtin_amdgcn_update_dpp(0, v, 0x142, 0xa, 0xf, true);
    v = __float_as_int(fmaxf(__int_as_float(v), __int_as_float(t)));
    t = __builtin_amdgcn_update_dpp(0, v, 0x143, 0xc, 0xf, true);
    v = __float_as_int(fmaxf(__int_as_float(v), __int_as_float(t)));
    return __int_as_float(__builtin_amdgcn_readlane(v, 63));
}

// ---------------- FPS: one 512-thread block per batch, 16 pts/thread in regs ----------------
// Evidence-driven structure (r0/r1/r2 post-mortems):
//  * Compute phase is pure-register after residency is fixed -> TLP need is
//    low; per-wave fixed overhead (tree/DPP/resolve/atomic) dominates extra
//    issue. 8 waves (512 thr) halves that vs 16 waves at equal update work.
//  * __launch_bounds__(512, 2): 2 waves/EU -> 256-VGPR cap. r1 (84 VGPR,
//    1 wave/EU) died of remat at zero TLP; r2 (32 VGPR) parked coords in
//    AGPRs (+~24 accvgpr_read/iter, VALUBusy 0.53->0.61 at same dur).
//    Pin is re-asserted INSIDE the loop to force arch-VGPR residency.
//  * One barrier per iteration via per-iteration u64 key slot
//    s_key[it] = (dist_bits<<32) | ~gi (dists >= 0 so float-bit order ==
//    unsigned order; ~gi -> smallest-index tie-break == numpy argmax).
//    Slots zero-initialized once; slot `it` written only before barrier `it`.
//  * Coords mirrored in LDS: post-barrier centroid fetch = 3 broadcast
//    ds_reads (~140cy) instead of global (~300cy) on the serial chain.
__global__ __launch_bounds__(512, 2) void fps_kernel(
    const float* __restrict__ xyz,
    float* __restrict__ nx_ws, float* __restrict__ out)
{
    int b = blockIdx.x;
    int tid = threadIdx.x;              // 0..511
    const float* X = xyz + b * 3 * NPTS;

    __shared__ float s_xyz[3 * NPTS];              // 96 KB coord mirror
    __shared__ unsigned long long s_key[NS];       // 8 KB

    float px[16], py[16], pz[16], dist[16];
#pragma unroll
    for (int i = 0; i < 16; ++i) {
        int gi = i * 512 + tid;                    // point index
        float x = X[gi], y = X[NPTS + gi], z = X[2 * NPTS + gi];
        px[i] = x; py[i] = y; pz[i] = z;
        dist[i] = 1e10f;
        s_xyz[gi] = x; s_xyz[NPTS + gi] = y; s_xyz[2 * NPTS + gi] = z;
    }
    for (int i = tid; i < NS; i += 512) s_key[i] = 0ull;
    if (tid == 0) s_key[0] = 0xFFFFFFFFull;        // idx 0 forced (value unused)
    __syncthreads();

    float cx = s_xyz[0], cy = s_xyz[NPTS], cz = s_xyz[2 * NPTS];

    for (int it = 1; it < NS; ++it) {
        // pin coords in arch VGPRs each iteration (defeat AGPR/remat games)
#pragma unroll
        for (int i = 0; i < 16; ++i)
            asm volatile("" : "+v"(px[i]), "+v"(py[i]), "+v"(pz[i]));
        // ---- update dists (exact numpy order, no fma) ----
#pragma unroll
        for (int i = 0; i < 16; ++i) {
            float dx = px[i] - cx, dy = py[i] - cy, dz = pz[i] - cz;
            float d = (dx * dx + dy * dy) + dz * dz;
            dist[i] = fminf(dist[i], d);
        }
        // ---- local value max (tree, 15 ops) ----
        float t8[8];
#pragma unroll
        for (int i = 0; i < 8; ++i) t8[i] = fmaxf(dist[2 * i], dist[2 * i + 1]);
        float t4[4];
#pragma unroll
        for (int i = 0; i < 4; ++i) t4[i] = fmaxf(t8[2 * i], t8[2 * i + 1]);
        float bv = fmaxf(fmaxf(t4[0], t4[1]), fmaxf(t4[2], t4[3]));
        // ---- wave max via DPP; winner lanes resolve first-index + one atomic ----
        float wm = wave_max_nonneg(bv);
        if (bv == wm) {
            int gi = 0;
#pragma unroll
            for (int i = 15; i >= 0; --i)
                if (dist[i] == wm) gi = i * 512 + tid;   // ends at smallest i
            unsigned long long key =
                ((unsigned long long)__float_as_uint(wm) << 32) | (unsigned)(~gi);
            atomicMax(&s_key[it], key);
        }
        __syncthreads();
        int idx = (int)(~(unsigned)s_key[it]);
        // centroid re-fetch: broadcast ds_read x3 (uniform address)
        cx = s_xyz[idx]; cy = s_xyz[NPTS + idx]; cz = s_xyz[2 * NPTS + idx];
    }

    // ---- outputs: fps indices + gathered new_xyz (all slots final) ----
    float* out_fps = out + 268288 + b * NS;
    for (int i = tid; i < NS; i += 512) {
        int j = (int)(~(unsigned)s_key[i]);
        out_fps[i] = (float)j;
        float x = s_xyz[j], y = s_xyz[NPTS + j], z = s_xyz[2 * NPTS + j];
        nx_ws[(b * 3 + 0) * NS + i] = x; out[(b * 3 + 0) * NS + i] = x;
        nx_ws[(b * 3 + 1) * NS + i] = y; out[(b * 3 + 1) * NS + i] = y;
        nx_ws[(b * 3 + 2) * NS + i] = z; out[(b * 3 + 2) * NS + i] = z;
    }
}

// ---------------- KNN: one wave per query ----------------
__global__ __launch_bounds__(256) void knn_kernel(
    const float* __restrict__ nx_ws, int* __restrict__ knn_ws)
{
    int q = blockIdx.x * 4 + (threadIdx.x >> 6);
    int lane = threadIdx.x & 63;
    int b = q >> 10, s = q & 1023;
    const float* P = nx_ws + b * 3 * NS;
    float qx = P[s], qy = P[NS + s], qz = P[2 * NS + s];
    float sqq = (qx * qx + qy * qy) + qz * qz;
    int base_j = lane * 16;
    float d2[16];
    {
        const float4* x4 = (const float4*)(P + base_j);
        const float4* y4 = (const float4*)(P + NS + base_j);
        const float4* z4 = (const float4*)(P + 2 * NS + base_j);
#pragma unroll
        for (int t = 0; t < 4; ++t) {
            float4 xv = x4[t], yv = y4[t], zv = z4[t];
            float xs[4] = { xv.x, xv.y, xv.z, xv.w };
            float ys[4] = { yv.x, yv.y, yv.z, yv.w };
            float zs[4] = { zv.x, zv.y, zv.z, zv.w };
#pragma unroll
            for (int e = 0; e < 4; ++e) {
                float xj = xs[e], yj = ys[e], zj = zs[e];
                float sqj = (xj * xj + yj * yj) + zj * zj;
                float dot = (qx * xj + qy * yj) + qz * zj;
                d2[t * 4 + e] = (sqq + sqj) - 2.0f * dot;   // numpy order
            }
        }
    }
    for (int r = 0; r < NK; ++r) {
        float lv = 3.0e38f; int li = 0;
#pragma unroll
        for (int i = 0; i < 16; ++i) { if (d2[i] < lv) { lv = d2[i]; li = i; } } // strict < keeps earliest
        int gj = base_j + li;
#pragma unroll
        for (int off = 32; off > 0; off >>= 1) {
            float ov = __shfl_xor(lv, off, 64);
            int   oj = __shfl_xor(gj, off, 64);
            if (ov < lv || (ov == lv && oj < gj)) { lv = ov; gj = oj; }
        }
        if (lane == 0) knn_ws[q * NK + r] = gj;
        if ((gj >> 4) == lane) {
            int li2 = gj & 15;
#pragma unroll
            for (int i = 0; i < 16; ++i) if (i == li2) d2[i] = 3.0e38f;
        }
    }
}

// ---------------- conv0 inner helper (positions compile-time per parity of g) ----------------
template<int GODD>
__device__ __forceinline__ void conv0_accum(
    const float* __restrict__ x0r, const float* __restrict__ wbase, float acc[9])
{
    for (int ic2 = 0; ic2 < 128; ++ic2) {
        const float4* x4 = (const float4*)(x0r + ic2 * 64);
        float rr[32];
#pragma unroll
        for (int j = 0; j < 4; ++j) {
            float4 t0 = x4[j * 2], t1 = x4[j * 2 + 1];
            rr[j*8+0]=t0.x; rr[j*8+1]=t0.y; rr[j*8+2]=t0.z; rr[j*8+3]=t0.w;
            rr[j*8+4]=t1.x; rr[j*8+5]=t1.y; rr[j*8+6]=t1.z; rr[j*8+7]=t1.w;
        }
        float w[9];
#pragma unroll
        for (int t = 0; t < 9; ++t) w[t] = wbase[(ic2 * 9 + t) * 64];
#pragma unroll
        for (int pp = 0; pp < 9; ++pp) {
            const int ly = GODD ? (pp < 3 ? 0 : 1) : (pp < 6 ? 0 : 1);
            const int xx = GODD ? (pp < 3 ? pp + 3 : pp - 3) : (pp < 6 ? pp : pp - 6);
#pragma unroll
            for (int ky = 0; ky < 3; ++ky)
#pragma unroll
                for (int kx = 0; kx < 3; ++kx)
                    acc[pp] = __builtin_fmaf(w[ky * 3 + kx], rr[(ly + ky) * 8 + xx + kx], acc[pp]);
        }
    }
}

// ---------------- per-sample conv chain ----------------
__global__ __launch_bounds__(256) void conv_kernel(
    const float* __restrict__ feats, const float* __restrict__ nx_ws,
    const int* __restrict__ knn_ws,
    const float* __restrict__ w0t, const float* __restrict__ bias0,
    const float* __restrict__ w1t, const float* __restrict__ w2t,
    const float* __restrict__ w3t, float* __restrict__ out)
{
    __shared__ float s_fg[512];       // [d][k]
    __shared__ int   s_ni[16];
    __shared__ float s_x0[8192];      // [ic2][u*8+v], outer channels only
    __shared__ float s_a1[64 * 36];
    __shared__ float s_a2[64 * 16];
    __shared__ float s_a3[128 * 4];

    int bs = blockIdx.x, b = bs >> 10, s = bs & 1023;
    int tid = threadIdx.x;
    if (tid < 16) s_ni[tid] = knn_ws[bs * NK + tid];
    __syncthreads();
    const float* P = nx_ws + b * 3 * NS;
#pragma unroll
    for (int e = tid; e < 512; e += 256) {
        int d = e >> 4, k = e & 15; int j = s_ni[k];
        float v = (d < 3) ? (P[d * NS + j] - P[d * NS + s])
                          : feats[(b * NC + (d - 3)) * NPTS + j];
        s_fg[e] = v;
    }
    __syncthreads();
    for (int e = tid; e < 8192; e += 256) {
        int ic2 = e >> 6, pos = e & 63, u = pos >> 3, v = pos & 7;
        int q = ic2 >> 5, ch = ic2 & 31;
        int ro = q & 1, co = ((q + 1) >> 1) & 1;    // tl,br,tr,bl
        s_x0[e] = s_fg[ch * 16 + 2 * u + ro] * s_fg[ch * 16 + 2 * v + co];
    }
    __syncthreads();

    int o = tid & 63, g = tid >> 6;
    { // conv0: 64 out-ch x 6x6, K = 128x9 (+ bias from ones-channels)
        int r0 = g + (g >> 1);
        float acc[9];
        float bz = bias0[o];
#pragma unroll
        for (int p = 0; p < 9; ++p) acc[p] = bz;
        const float* x0r = s_x0 + r0 * 8;
        const float* wb = w0t + o;
        if (g & 1) conv0_accum<1>(x0r, wb, acc);
        else       conv0_accum<0>(x0r, wb, acc);
#pragma unroll
        for (int pp = 0; pp < 9; ++pp) s_a1[o * 36 + g * 9 + pp] = fmaxf(acc[pp], 0.0f);
    }
    __syncthreads();
    { // conv1: 64 x 4x4, K = 64x9 ; y = g
        float a[4] = {0, 0, 0, 0};
        const float* wb = w1t + o;
        for (int ic = 0; ic < 64; ++ic) {
            const float2* ar2 = (const float2*)(s_a1 + ic * 36 + g * 6);
            float r[18];
#pragma unroll
            for (int t = 0; t < 9; ++t) { float2 tv = ar2[t]; r[t*2] = tv.x; r[t*2+1] = tv.y; }
            float w[9];
#pragma unroll
            for (int t = 0; t < 9; ++t) w[t] = wb[(ic * 9 + t) * 64];
#pragma unroll
            for (int x = 0; x < 4; ++x)
#pragma unroll
                for (int ky = 0; ky < 3; ++ky)
#pragma unroll
                    for (int kx = 0; kx < 3; ++kx)
                        a[x] = __builtin_fmaf(w[ky * 3 + kx], r[ky * 6 + x + kx], a[x]);
        }
#pragma unroll
        for (int x = 0; x < 4; ++x) s_a2[o * 16 + g * 4 + x] = fmaxf(a[x], 0.0f);
    }
    __syncthreads();
    { // conv2: 128 x 2x2, K = 64x9 ; y = g2
        int o2 = tid & 127, g2 = tid >> 7;
        float a[2] = {0, 0};
        const float* wb = w2t + o2;
        for (int ic = 0; ic < 64; ++ic) {
            const float4* ar4 = (const float4*)(s_a2 + ic * 16 + g2 * 4);
            float r[12];
#pragma unroll
            for (int t = 0; t < 3; ++t) { float4 tv = ar4[t]; r[t*4]=tv.x; r[t*4+1]=tv.y; r[t*4+2]=tv.z; r[t*4+3]=tv.w; }
            float w[9];
#pragma unroll
            for (int t = 0; t < 9; ++t) w[t] = wb[(ic * 9 + t) * 128];
#pragma unroll
            for (int x = 0; x < 2; ++x)
#pragma unroll
                for (int ky = 0; ky < 3; ++ky)
#pragma unroll
                    for (int kx = 0; kx < 3; ++kx)
                        a[x] = __builtin_fmaf(w[ky * 3 + kx], r[ky * 4 + x + kx], a[x]);
        }
#pragma unroll
        for (int x = 0; x < 2; ++x) s_a3[o2 * 4 + g2 * 2 + x] = fmaxf(a[x], 0.0f);
    }
    __syncthreads();
    // conv3: 128 out, K = 128x4 -> 1x1, relu, write new_points
    if (tid < 128) {
        float acc = 0.0f;
        const float* wb = w3t + tid;
        for (int ic = 0; ic < 128; ++ic) {
            float4 av = *(const float4*)(s_a3 + ic * 4);
            float wa = wb[(ic * 4 + 0) * 128];
            float wbv = wb[(ic * 4 + 1) * 128];
            float wc = wb[(ic * 4 + 2) * 128];
            float wd = wb[(ic * 4 + 3) * 128];
            acc = __builtin_fmaf(wa, av.x, acc);
            acc = __builtin_fmaf(wbv, av.y, acc);
            acc = __builtin_fmaf(wc, av.z, acc);
            acc = __builtin_fmaf(wd, av.w, acc);
        }
        out[6144 + (b * 128 + tid) * NS + s] = fmaxf(acc, 0.0f);
    }
}

extern "C" void kernel_launch(void* const* d_in, const int* in_sizes, int n_in,
                              void* d_out, int out_size, void* d_ws, size_t ws_size,
                              hipStream_t stream) {
    const float* xyz   = (const float*)d_in[0];
    const float* feats = (const float*)d_in[1];
    const float* w0    = (const float*)d_in[2];
    const float* w1    = (const float*)d_in[3];
    const float* w2    = (const float*)d_in[4];
    const float* w3    = (const float*)d_in[5];
    float* out = (float*)d_out;

    char* ws = (char*)d_ws;
    float* nx_ws  = (float*)(ws + 8192);
    int*   knn_ws = (int*)(ws + 32768);
    float* w0t    = (float*)(ws + 163840);
    float* bias0  = (float*)(ws + 458752);
    float* w1t    = (float*)(ws + 459008);
    float* w2t    = (float*)(ws + 606464);
    float* w3t    = (float*)(ws + 901376);

    prep_kernel<<<128, 256, 0, stream>>>(w0, w1, w2, w3, w0t, w1t, w2t, w3t, bias0);
    fps_kernel<<<NB, 512, 0, stream>>>(xyz, nx_ws, out);
    knn_kernel<<<(NB * NS) / 4, 256, 0, stream>>>(nx_ws, knn_ws);
    conv_kernel<<<NB * NS, 256, 0, stream>>>(feats, nx_ws, knn_ws, w0t, bias0, w1t, w2t, w3t, out);
}